// Round 2
// baseline (1936.260 us; speedup 1.0000x reference)
//
#include <hip/hip_runtime.h>
#include <hip/hip_bf16.h>

#define BT 65536
#define DD 512
#define HH 512
#define NE 32
#define CAP 5120
#define BM 64
#define NRB 80   /* CAP/BM */
#define GTOK 256 /* tokens per gate block */

typedef float  f32x4  __attribute__((ext_vector_type(4)));
typedef short  bf16x8 __attribute__((ext_vector_type(8)));

__device__ __forceinline__ unsigned short f2bf(float f){
    unsigned int u = __builtin_bit_cast(unsigned int, f);
    unsigned int r = (u + 0x7fffu + ((u >> 16) & 1u)) >> 16;
    return (unsigned short)r;
}

// ---------------- weight transpose + bf16 convert ----------------
// W[e][k][n] fp32  ->  WT[e][n][k] bf16
__global__ __launch_bounds__(256) void k_wconv(
    const float* __restrict__ W1, const float* __restrict__ W2,
    unsigned short* __restrict__ W1T, unsigned short* __restrict__ W2T)
{
    int bid = blockIdx.x;
    const float* src = W1; unsigned short* dst = W1T;
    if (bid >= 2048){ src = W2; dst = W2T; bid -= 2048; }
    int e    = bid >> 6;
    int trow = (bid >> 3) & 7;   // k-tile
    int tcol = bid & 7;          // n-tile
    __shared__ float tile[64][65];
    const float* base = src + ((size_t)e << 18);
    int t = threadIdx.x;
    #pragma unroll
    for (int i = 0; i < 16; i++){
        int idx = i*256 + t;
        int k = idx >> 6, n = idx & 63;
        tile[k][n] = base[(size_t)(trow*64 + k)*512 + tcol*64 + n];
    }
    __syncthreads();
    unsigned short* ob = dst + ((size_t)e << 18);
    #pragma unroll
    for (int i = 0; i < 16; i++){
        int idx = i*256 + t;
        int n = idx >> 6, k = idx & 63;
        ob[(size_t)(tcol*64 + n)*512 + trow*64 + k] = f2bf(tile[k][n]);
    }
}

// ---------------- gating v2: fp32 register-blocked GEMM + rare fp64 fallback ----------------
__global__ __launch_bounds__(256, 1) void k_gate(
    const float* __restrict__ x, const float* __restrict__ Wg,
    float* __restrict__ y, int* __restrict__ counts,
    int* __restrict__ toks, float* __restrict__ wts)
{
    __shared__ float WgS[DD * NE];          // 64 KB, [d][n]
    __shared__ float xT[32][GTOK + 1];      // 32.9 KB, [d'][token], padded
    __shared__ int   lcnt[NE], lbase[NE];

    int tid = threadIdx.x;
    int r0  = blockIdx.x * GTOK;
    int tok = r0 + tid;

    // stage Wg into LDS (same flat layout, coalesced)
    #pragma unroll
    for (int i = 0; i < 16; i++){
        int f = i*1024 + tid*4;
        *(float4*)&WgS[f] = *(const float4*)&Wg[f];
    }

    float acc[NE];
    #pragma unroll
    for (int n = 0; n < NE; n++) acc[n] = 0.f;

    const int prow = tid >> 3;        // 0..31  (token sub-row per pass)
    const int pcol = (tid & 7) * 4;   // 0..28  (d' within chunk)
    float4 pf[8];
    #pragma unroll
    for (int p = 0; p < 8; p++)
        pf[p] = *(const float4*)&x[(size_t)(r0 + p*32 + prow)*DD + pcol];

    __syncthreads();   // WgS ready
    #pragma unroll
    for (int p = 0; p < 8; p++){
        int tk = p*32 + prow;
        xT[pcol+0][tk] = pf[p].x; xT[pcol+1][tk] = pf[p].y;
        xT[pcol+2][tk] = pf[p].z; xT[pcol+3][tk] = pf[p].w;
    }
    __syncthreads();

    #pragma unroll 1
    for (int c = 0; c < 16; c++){
        if (c < 15){
            #pragma unroll
            for (int p = 0; p < 8; p++)
                pf[p] = *(const float4*)&x[(size_t)(r0 + p*32 + prow)*DD + (c+1)*32 + pcol];
        }
        #pragma unroll
        for (int dd = 0; dd < 32; dd++){
            float xv = xT[dd][tid];
            const float4* wrow = (const float4*)&WgS[(c*32 + dd)*NE];
            #pragma unroll
            for (int q = 0; q < 8; q++){
                float4 w4 = wrow[q];
                acc[q*4+0] = fmaf(xv, w4.x, acc[q*4+0]);
                acc[q*4+1] = fmaf(xv, w4.y, acc[q*4+1]);
                acc[q*4+2] = fmaf(xv, w4.z, acc[q*4+2]);
                acc[q*4+3] = fmaf(xv, w4.w, acc[q*4+3]);
            }
        }
        if (c < 15){
            __syncthreads();
            #pragma unroll
            for (int p = 0; p < 8; p++){
                int tk = p*32 + prow;
                xT[pcol+0][tk] = pf[p].x; xT[pcol+1][tk] = pf[p].y;
                xT[pcol+2][tk] = pf[p].z; xT[pcol+3][tk] = pf[p].w;
            }
            __syncthreads();
        }
    }

    // top-3 in fp32 (strict > keeps lowest index on ties, matching lax.top_k)
    float v1 = -1e30f; int i1 = -1;
    #pragma unroll
    for (int n = 0; n < NE; n++) if (acc[n] > v1){ v1 = acc[n]; i1 = n; }
    float v2 = -1e30f; int i2 = -1;
    #pragma unroll
    for (int n = 0; n < NE; n++) if (n != i1 && acc[n] > v2){ v2 = acc[n]; i2 = n; }
    float v3 = -1e30f;
    #pragma unroll
    for (int n = 0; n < NE; n++) if (n != i1 && n != i2 && acc[n] > v3) v3 = acc[n];

    float w1, w2;
    if (v2 - v3 < 1e-4f){
        // rare: fp64 recompute to resolve the {top2} set exactly
        double a64[NE];
        #pragma unroll
        for (int n = 0; n < NE; n++) a64[n] = 0.0;
        const float* xr = x + (size_t)tok * DD;
        #pragma unroll 1
        for (int d = 0; d < DD; d++){
            double xv = (double)xr[d];
            #pragma unroll
            for (int n = 0; n < NE; n++)
                a64[n] = fma(xv, (double)WgS[d*NE + n], a64[n]);
        }
        double dv1 = -1e300; i1 = -1;
        #pragma unroll 1
        for (int n = 0; n < NE; n++) if (a64[n] > dv1){ dv1 = a64[n]; i1 = n; }
        double dv2 = -1e300; i2 = -1;
        #pragma unroll 1
        for (int n = 0; n < NE; n++) if (n != i1 && a64[n] > dv2){ dv2 = a64[n]; i2 = n; }
        double ex  = exp(dv2 - dv1);
        double inv = 1.0 / (1.0 + ex);
        w1 = (float)inv; w2 = (float)(ex * inv);
    } else {
        double ex  = exp((double)v2 - (double)v1);
        double inv = 1.0 / (1.0 + ex);
        w1 = (float)inv; w2 = (float)(ex * inv);
    }

    // two-level slot assignment
    if (tid < NE) lcnt[tid] = 0;
    __syncthreads();
    int s1 = atomicAdd(&lcnt[i1], 1);
    int s2 = atomicAdd(&lcnt[i2], 1);
    __syncthreads();
    if (tid < NE && lcnt[tid] > 0) lbase[tid] = atomicAdd(&counts[tid], lcnt[tid]);
    __syncthreads();
    int g1 = lbase[i1] + s1;
    int g2 = lbase[i2] + s2;
    bool k1 = g1 < CAP, k2 = g2 < CAP;
    if (k1){ toks[i1*CAP + g1] = tok; wts[i1*CAP + g1] = w1; }
    if (k2){ toks[i2*CAP + g2] = tok; wts[i2*CAP + g2] = w2; }

    // cooperative coalesced y zero for this block's 256 rows
    float4 z4; z4.x = 0.f; z4.y = 0.f; z4.z = 0.f; z4.w = 0.f;
    float4* yb = (float4*)(y + (size_t)r0 * DD);
    #pragma unroll 1
    for (int i = 0; i < 128; i++) yb[i*256 + tid] = z4;
    __syncthreads();
    if (!(k1 | k2)){   // passthrough (statistically never happens)
        const float4* xr4 = (const float4*)(x + (size_t)tok * DD);
        float4* yr4 = (float4*)(y + (size_t)tok * DD);
        #pragma unroll 1
        for (int j = 0; j < 128; j++) yr4[j] = xr4[j];
    }
}

// ---------------- fused expert FFN: relu(Xg@W1+b1)@W2+b2, scatter-add ----------------
__global__ __launch_bounds__(512, 2) void k_ffn(
    const float* __restrict__ x,
    const unsigned short* __restrict__ W1T,
    const unsigned short* __restrict__ W2T,
    const float* __restrict__ b1, const float* __restrict__ b2,
    const int* __restrict__ counts,
    const int* __restrict__ toks, const float* __restrict__ wts,
    float* __restrict__ y)
{
    __shared__ unsigned char AH[64 * 1024];      // 64 rows x 512 bf16, 16B-chunk XOR swizzle (r&7)
    __shared__ unsigned char Bb[2][32 * 1024];   // 512 rows x 32 bf16 (64B rows), chunk XOR ((n>>1)&3)

    int e  = blockIdx.x / NRB;
    int rb = blockIdx.x % NRB;
    int cnt = counts[e]; if (cnt > CAP) cnt = CAP;
    int r0 = rb * BM;
    if (r0 >= cnt) return;

    int tid  = threadIdx.x;
    int lane = tid & 63;
    int wid  = tid >> 6;
    int wm = wid >> 2;       // 0..1 : 32-row half
    int wn = wid & 3;        // 0..3 : 128-col slice

    // ---- stage A: gather x rows, convert to bf16, swizzled ----
    {
        int row = tid >> 3, seg = tid & 7;
        int gr  = r0 + row;
        char* rowb = (char*)AH + row * 1024;
        int rsw = (row & 7) << 4;
        if (gr < cnt){
            int tk = toks[e*CAP + gr];
            const float4* src = (const float4*)(x + (size_t)tk*DD + seg*64);
            #pragma unroll
            for (int j = 0; j < 8; j++){
                float4 f0 = src[2*j], f1 = src[2*j+1];
                bf16x8 p;
                p[0]=(short)f2bf(f0.x); p[1]=(short)f2bf(f0.y); p[2]=(short)f2bf(f0.z); p[3]=(short)f2bf(f0.w);
                p[4]=(short)f2bf(f1.x); p[5]=(short)f2bf(f1.y); p[6]=(short)f2bf(f1.z); p[7]=(short)f2bf(f1.w);
                int chunk = seg*8 + j;
                *(bf16x8*)(rowb + ((chunk << 4) ^ rsw)) = p;
            }
        } else {
            bf16x8 zz = (bf16x8)0;
            #pragma unroll
            for (int j = 0; j < 8; j++){
                int chunk = seg*8 + j;
                *(bf16x8*)(rowb + ((chunk << 4) ^ rsw)) = zz;
            }
        }
    }

    float bias1[8], bias2[8];
    #pragma unroll
    for (int nf = 0; nf < 8; nf++){
        int col = wn*128 + nf*16 + (lane & 15);
        bias1[nf] = b1[e*HH + col];
        bias2[nf] = b2[e*DD + col];
    }

    f32x4 acc[2][8];
    #pragma unroll
    for (int mf = 0; mf < 2; mf++)
        #pragma unroll
        for (int nf = 0; nf < 8; nf++)
            acc[mf][nf] = (f32x4)0.f;

    // B chunk c: layer = c>>4, kk = (c&15)*32; thread stages 4 x 16B
    bf16x8 stg[4];
    {   // prologue chunk 0
        const unsigned short* Wb = W1T + ((size_t)e << 18);
        #pragma unroll
        for (int j = 0; j < 4; j++){
            int m = j*512 + tid; int n = m >> 2, cd = m & 3;
            stg[j] = *(const bf16x8*)(Wb + (size_t)n*512 + cd*8);
        }
        char* lb = (char*)Bb[0];
        #pragma unroll
        for (int j = 0; j < 4; j++){
            int m = j*512 + tid; int n = m >> 2, cd = m & 3;
            *(bf16x8*)(lb + n*64 + ((cd ^ ((n >> 1) & 3)) << 4)) = stg[j];
        }
    }
    __syncthreads();

    int cur = 0;
    #pragma unroll 1
    for (int c = 0; c < 32; c++){
        if (c < 31){
            int cn = c + 1;
            const unsigned short* Wb = ((cn < 16) ? W1T : W2T) + ((size_t)e << 18) + (cn & 15)*32;
            #pragma unroll
            for (int j = 0; j < 4; j++){
                int m = j*512 + tid; int n = m >> 2, cd = m & 3;
                stg[j] = *(const bf16x8*)(Wb + (size_t)n*512 + cd*8);
            }
        }
        // compute chunk c
        {
            bf16x8 a[2], b[8];
            int kchunk0 = ((c & 15) << 2) + (lane >> 4);
            #pragma unroll
            for (int mf = 0; mf < 2; mf++){
                int r = wm*32 + mf*16 + (lane & 15);
                a[mf] = *(const bf16x8*)((char*)AH + r*1024 + ((kchunk0 ^ (r & 7)) << 4));
            }
            int cd = lane >> 4;
            #pragma unroll
            for (int nf = 0; nf < 8; nf++){
                int n = wn*128 + nf*16 + (lane & 15);
                b[nf] = *(const bf16x8*)((char*)Bb[cur] + n*64 + ((cd ^ ((n >> 1) & 3)) << 4));
            }
            #pragma unroll
            for (int mf = 0; mf < 2; mf++)
                #pragma unroll
                for (int nf = 0; nf < 8; nf++)
                    acc[mf][nf] = __builtin_amdgcn_mfma_f32_16x16x32_bf16(a[mf], b[nf], acc[mf][nf], 0, 0, 0);
        }

        if (c == 15){
            __syncthreads();   // all waves done reading X from AH
            #pragma unroll
            for (int mf = 0; mf < 2; mf++){
                #pragma unroll
                for (int nf = 0; nf < 8; nf++){
                    int col = wn*128 + nf*16 + (lane & 15);
                    #pragma unroll
                    for (int i = 0; i < 4; i++){
                        int r = wm*32 + mf*16 + ((lane >> 4) << 2) + i;
                        float h = acc[mf][nf][i] + bias1[nf];
                        h = h > 0.f ? h : 0.f;
                        char* p = (char*)AH + r*1024 + ((((col >> 3) ^ (r & 7)) << 4)) + (col & 7)*2;
                        *(unsigned short*)p = f2bf(h);
                        acc[mf][nf][i] = 0.f;
                    }
                }
            }
        }

        if (c < 31){
            char* lb = (char*)Bb[cur ^ 1];
            #pragma unroll
            for (int j = 0; j < 4; j++){
                int m = j*512 + tid; int n = m >> 2, cd = m & 3;
                *(bf16x8*)(lb + n*64 + ((cd ^ ((n >> 1) & 3)) << 4)) = stg[j];
            }
        }
        __syncthreads();
        cur ^= 1;
    }

    // epilogue: o = acc + b2; y[tok] += w * o
    #pragma unroll
    for (int mf = 0; mf < 2; mf++){
        #pragma unroll
        for (int i = 0; i < 4; i++){
            int rl = wm*32 + mf*16 + ((lane >> 4) << 2) + i;
            int gr = r0 + rl;
            if (gr < cnt){
                int   tk = toks[e*CAP + gr];
                float w  = wts[e*CAP + gr];
                float* yr = y + (size_t)tk * DD;
                #pragma unroll
                for (int nf = 0; nf < 8; nf++){
                    int col = wn*128 + nf*16 + (lane & 15);
                    atomicAdd(yr + col, w * (acc[mf][nf][i] + bias2[nf]));
                }
            }
        }
    }
}

extern "C" void kernel_launch(void* const* d_in, const int* in_sizes, int n_in,
                              void* d_out, int out_size, void* d_ws, size_t ws_size,
                              hipStream_t stream)
{
    const float* x  = (const float*)d_in[0];
    const float* Wg = (const float*)d_in[1];
    const float* W1 = (const float*)d_in[2];
    const float* b1 = (const float*)d_in[3];
    const float* W2 = (const float*)d_in[4];
    const float* b2 = (const float*)d_in[5];
    float* y = (float*)d_out;

    char* ws = (char*)d_ws;
    unsigned short* W1T = (unsigned short*)(ws);
    unsigned short* W2T = (unsigned short*)(ws + 16777216);
    int*   counts = (int*)  (ws + 33554432);
    int*   toks   = (int*)  (ws + 33554432 + 256);
    float* wts    = (float*)(ws + 33554432 + 256 + 655360);

    hipMemsetAsync(counts, 0, 256, stream);
    hipLaunchKernelGGL(k_wconv, dim3(4096), dim3(256), 0, stream, W1, W2, W1T, W2T);
    hipLaunchKernelGGL(k_gate,  dim3(BT/GTOK), dim3(256), 0, stream, x, Wg, y, counts, toks, wts);
    hipLaunchKernelGGL(k_ffn,   dim3(NE*NRB), dim3(512), 0, stream, x, W1T, W2T, b1, b2, counts, toks, wts, y);
}

// Round 3
// 1750.883 us; speedup vs baseline: 1.1059x; 1.1059x over previous
//
#include <hip/hip_runtime.h>
#include <hip/hip_bf16.h>

#define BT 65536
#define DD 512
#define HH 512
#define NE 32
#define CAP 5120
#define BM 64
#define NRB 80   /* CAP/BM */
#define GTOK 256 /* tokens per gate block */

typedef float  f32x4  __attribute__((ext_vector_type(4)));
typedef short  bf16x8 __attribute__((ext_vector_type(8)));

__device__ __forceinline__ unsigned short f2bf(float f){
    unsigned int u = __builtin_bit_cast(unsigned int, f);
    unsigned int r = (u + 0x7fffu + ((u >> 16) & 1u)) >> 16;
    return (unsigned short)r;
}

// ---------------- weight transpose + bf16 convert ----------------
// W[e][k][n] fp32  ->  WT[e][n][k] bf16
__global__ __launch_bounds__(256) void k_wconv(
    const float* __restrict__ W1, const float* __restrict__ W2,
    unsigned short* __restrict__ W1T, unsigned short* __restrict__ W2T)
{
    int bid = blockIdx.x;
    const float* src = W1; unsigned short* dst = W1T;
    if (bid >= 2048){ src = W2; dst = W2T; bid -= 2048; }
    int e    = bid >> 6;
    int trow = (bid >> 3) & 7;   // k-tile
    int tcol = bid & 7;          // n-tile
    __shared__ float tile[64][65];
    const float* base = src + ((size_t)e << 18);
    int t = threadIdx.x;
    #pragma unroll
    for (int i = 0; i < 16; i++){
        int idx = i*256 + t;
        int k = idx >> 6, n = idx & 63;
        tile[k][n] = base[(size_t)(trow*64 + k)*512 + tcol*64 + n];
    }
    __syncthreads();
    unsigned short* ob = dst + ((size_t)e << 18);
    #pragma unroll
    for (int i = 0; i < 16; i++){
        int idx = i*256 + t;
        int n = idx >> 6, k = idx & 63;
        ob[(size_t)(tcol*64 + n)*512 + trow*64 + k] = f2bf(tile[k][n]);
    }
}

// ---------------- gating v3: fp32 register GEMM + array-free fp64 candidate fallback ----------------
__global__ __launch_bounds__(256, 1) void k_gate(
    const float* __restrict__ x, const float* __restrict__ Wg,
    float* __restrict__ y, int* __restrict__ counts,
    int* __restrict__ toks, float* __restrict__ wts)
{
    __shared__ float WgS[DD * NE];          // 64 KB, [d][n]
    __shared__ float xT[32][GTOK + 1];      // 32.9 KB, [d'][token], padded
    __shared__ int   lcnt[NE], lbase[NE];

    int tid = threadIdx.x;
    int r0  = blockIdx.x * GTOK;
    int tok = r0 + tid;

    // stage Wg into LDS (same flat layout, coalesced)
    #pragma unroll
    for (int i = 0; i < 16; i++){
        int f = i*1024 + tid*4;
        *(float4*)&WgS[f] = *(const float4*)&Wg[f];
    }

    float acc[NE];
    #pragma unroll
    for (int n = 0; n < NE; n++) acc[n] = 0.f;

    const int prow = tid >> 3;        // 0..31  (token sub-row per pass)
    const int pcol = (tid & 7) * 4;   // 0..28  (d' within chunk)
    float4 pf[8];
    #pragma unroll
    for (int p = 0; p < 8; p++)
        pf[p] = *(const float4*)&x[(size_t)(r0 + p*32 + prow)*DD + pcol];

    __syncthreads();   // WgS ready
    #pragma unroll
    for (int p = 0; p < 8; p++){
        int tk = p*32 + prow;
        xT[pcol+0][tk] = pf[p].x; xT[pcol+1][tk] = pf[p].y;
        xT[pcol+2][tk] = pf[p].z; xT[pcol+3][tk] = pf[p].w;
    }
    __syncthreads();

    #pragma unroll 1
    for (int c = 0; c < 16; c++){
        if (c < 15){
            #pragma unroll
            for (int p = 0; p < 8; p++)
                pf[p] = *(const float4*)&x[(size_t)(r0 + p*32 + prow)*DD + (c+1)*32 + pcol];
        }
        #pragma unroll
        for (int dd = 0; dd < 32; dd++){
            float xv = xT[dd][tid];
            const float4* wrow = (const float4*)&WgS[(c*32 + dd)*NE];
            #pragma unroll
            for (int q = 0; q < 8; q++){
                float4 w4 = wrow[q];
                acc[q*4+0] = fmaf(xv, w4.x, acc[q*4+0]);
                acc[q*4+1] = fmaf(xv, w4.y, acc[q*4+1]);
                acc[q*4+2] = fmaf(xv, w4.z, acc[q*4+2]);
                acc[q*4+3] = fmaf(xv, w4.w, acc[q*4+3]);
            }
        }
        if (c < 15){
            __syncthreads();
            #pragma unroll
            for (int p = 0; p < 8; p++){
                int tk = p*32 + prow;
                xT[pcol+0][tk] = pf[p].x; xT[pcol+1][tk] = pf[p].y;
                xT[pcol+2][tk] = pf[p].z; xT[pcol+3][tk] = pf[p].w;
            }
            __syncthreads();
        }
    }

    // top-3 in fp32 (strict > keeps lowest index on ties, matching lax.top_k)
    // NOTE: all acc[] indexing below is compile-time (fully unrolled) -> stays in VGPRs.
    float v1 = -1e30f; int i1 = -1;
    #pragma unroll
    for (int n = 0; n < NE; n++) if (acc[n] > v1){ v1 = acc[n]; i1 = n; }
    float v2 = -1e30f; int i2 = -1;
    #pragma unroll
    for (int n = 0; n < NE; n++) if (n != i1 && acc[n] > v2){ v2 = acc[n]; i2 = n; }
    float v3 = -1e30f;
    #pragma unroll
    for (int n = 0; n < NE; n++) if (n != i1 && n != i2 && acc[n] > v3) v3 = acc[n];

    float w1, w2;
    if (v2 - v3 >= 1e-4f){
        // common path: fp32 gap is decisive (fp32 accumulation error ~1e-6)
        double ex  = exp((double)v2 - (double)v1);
        double inv = 1.0 / (1.0 + ex);
        w1 = (float)inv; w2 = (float)(ex * inv);
    } else {
        // rare (~1e-3): resolve the {top2} set among near-tie candidates in fp64.
        // Candidate mask built with STATIC acc[] indexing (no scratch).
        float thresh = v2 - 1e-3f;
        unsigned cmask = 0u;
        #pragma unroll
        for (int n = 0; n < NE; n++) cmask |= (acc[n] >= thresh) ? (1u << n) : 0u;

        const float* xr = x + (size_t)tok * DD;
        double dv1 = -1.0e300, dv2 = -1.0e300; int di1 = -1, di2 = -1;
        #pragma unroll 1
        for (int n = 0; n < NE; n++){
            if (!((cmask >> n) & 1u)) continue;
            double s0 = 0.0, s1 = 0.0, s2 = 0.0, s3 = 0.0;
            #pragma unroll 4
            for (int d = 0; d < DD; d += 4){
                s0 = fma((double)xr[d+0], (double)WgS[(d+0)*NE + n], s0);
                s1 = fma((double)xr[d+1], (double)WgS[(d+1)*NE + n], s1);
                s2 = fma((double)xr[d+2], (double)WgS[(d+2)*NE + n], s2);
                s3 = fma((double)xr[d+3], (double)WgS[(d+3)*NE + n], s3);
            }
            double s = (s0 + s1) + (s2 + s3);
            if (s > dv1){ dv2 = dv1; di2 = di1; dv1 = s; di1 = n; }
            else if (s > dv2){ dv2 = s; di2 = n; }
        }
        i1 = di1; i2 = di2;
        double ex  = exp(dv2 - dv1);
        double inv = 1.0 / (1.0 + ex);
        w1 = (float)inv; w2 = (float)(ex * inv);
    }

    // two-level slot assignment
    if (tid < NE) lcnt[tid] = 0;
    __syncthreads();
    int s1 = atomicAdd(&lcnt[i1], 1);
    int s2 = atomicAdd(&lcnt[i2], 1);
    __syncthreads();
    if (tid < NE && lcnt[tid] > 0) lbase[tid] = atomicAdd(&counts[tid], lcnt[tid]);
    __syncthreads();
    int g1 = lbase[i1] + s1;
    int g2 = lbase[i2] + s2;
    bool k1 = g1 < CAP, k2 = g2 < CAP;
    if (k1){ toks[i1*CAP + g1] = tok; wts[i1*CAP + g1] = w1; }
    if (k2){ toks[i2*CAP + g2] = tok; wts[i2*CAP + g2] = w2; }

    // cooperative coalesced y zero for this block's 256 rows
    float4 z4; z4.x = 0.f; z4.y = 0.f; z4.z = 0.f; z4.w = 0.f;
    float4* yb = (float4*)(y + (size_t)r0 * DD);
    #pragma unroll 1
    for (int i = 0; i < 128; i++) yb[i*256 + tid] = z4;
    __syncthreads();
    if (!(k1 | k2)){   // passthrough (statistically never happens)
        const float4* xr4 = (const float4*)(x + (size_t)tok * DD);
        float4* yr4 = (float4*)(y + (size_t)tok * DD);
        #pragma unroll 1
        for (int j = 0; j < 128; j++) yr4[j] = xr4[j];
    }
}

// ---------------- fused expert FFN: relu(Xg@W1+b1)@W2+b2, scatter-add ----------------
__global__ __launch_bounds__(512, 2) void k_ffn(
    const float* __restrict__ x,
    const unsigned short* __restrict__ W1T,
    const unsigned short* __restrict__ W2T,
    const float* __restrict__ b1, const float* __restrict__ b2,
    const int* __restrict__ counts,
    const int* __restrict__ toks, const float* __restrict__ wts,
    float* __restrict__ y)
{
    __shared__ unsigned char AH[64 * 1024];      // 64 rows x 512 bf16, 16B-chunk XOR swizzle (r&7)
    __shared__ unsigned char Bb[2][32 * 1024];   // 512 rows x 32 bf16 (64B rows), chunk XOR ((n>>1)&3)

    int e  = blockIdx.x / NRB;
    int rb = blockIdx.x % NRB;
    int cnt = counts[e]; if (cnt > CAP) cnt = CAP;
    int r0 = rb * BM;
    if (r0 >= cnt) return;

    int tid  = threadIdx.x;
    int lane = tid & 63;
    int wid  = tid >> 6;
    int wm = wid >> 2;       // 0..1 : 32-row half
    int wn = wid & 3;        // 0..3 : 128-col slice

    // ---- stage A: gather x rows, convert to bf16, swizzled ----
    {
        int row = tid >> 3, seg = tid & 7;
        int gr  = r0 + row;
        char* rowb = (char*)AH + row * 1024;
        int rsw = (row & 7) << 4;
        if (gr < cnt){
            int tk = toks[e*CAP + gr];
            const float4* src = (const float4*)(x + (size_t)tk*DD + seg*64);
            #pragma unroll
            for (int j = 0; j < 8; j++){
                float4 f0 = src[2*j], f1 = src[2*j+1];
                bf16x8 p;
                p[0]=(short)f2bf(f0.x); p[1]=(short)f2bf(f0.y); p[2]=(short)f2bf(f0.z); p[3]=(short)f2bf(f0.w);
                p[4]=(short)f2bf(f1.x); p[5]=(short)f2bf(f1.y); p[6]=(short)f2bf(f1.z); p[7]=(short)f2bf(f1.w);
                int chunk = seg*8 + j;
                *(bf16x8*)(rowb + ((chunk << 4) ^ rsw)) = p;
            }
        } else {
            bf16x8 zz = (bf16x8)0;
            #pragma unroll
            for (int j = 0; j < 8; j++){
                int chunk = seg*8 + j;
                *(bf16x8*)(rowb + ((chunk << 4) ^ rsw)) = zz;
            }
        }
    }

    float bias1[8], bias2[8];
    #pragma unroll
    for (int nf = 0; nf < 8; nf++){
        int col = wn*128 + nf*16 + (lane & 15);
        bias1[nf] = b1[e*HH + col];
        bias2[nf] = b2[e*DD + col];
    }

    f32x4 acc[2][8];
    #pragma unroll
    for (int mf = 0; mf < 2; mf++)
        #pragma unroll
        for (int nf = 0; nf < 8; nf++)
            acc[mf][nf] = (f32x4)0.f;

    // B chunk c: layer = c>>4, kk = (c&15)*32; thread stages 4 x 16B
    bf16x8 stg[4];
    {   // prologue chunk 0
        const unsigned short* Wb = W1T + ((size_t)e << 18);
        #pragma unroll
        for (int j = 0; j < 4; j++){
            int m = j*512 + tid; int n = m >> 2, cd = m & 3;
            stg[j] = *(const bf16x8*)(Wb + (size_t)n*512 + cd*8);
        }
        char* lb = (char*)Bb[0];
        #pragma unroll
        for (int j = 0; j < 4; j++){
            int m = j*512 + tid; int n = m >> 2, cd = m & 3;
            *(bf16x8*)(lb + n*64 + ((cd ^ ((n >> 1) & 3)) << 4)) = stg[j];
        }
    }
    __syncthreads();

    int cur = 0;
    #pragma unroll 1
    for (int c = 0; c < 32; c++){
        if (c < 31){
            int cn = c + 1;
            const unsigned short* Wb = ((cn < 16) ? W1T : W2T) + ((size_t)e << 18) + (cn & 15)*32;
            #pragma unroll
            for (int j = 0; j < 4; j++){
                int m = j*512 + tid; int n = m >> 2, cd = m & 3;
                stg[j] = *(const bf16x8*)(Wb + (size_t)n*512 + cd*8);
            }
        }
        // compute chunk c
        {
            bf16x8 a[2], b[8];
            int kchunk0 = ((c & 15) << 2) + (lane >> 4);
            #pragma unroll
            for (int mf = 0; mf < 2; mf++){
                int r = wm*32 + mf*16 + (lane & 15);
                a[mf] = *(const bf16x8*)((char*)AH + r*1024 + ((kchunk0 ^ (r & 7)) << 4));
            }
            int cd = lane >> 4;
            #pragma unroll
            for (int nf = 0; nf < 8; nf++){
                int n = wn*128 + nf*16 + (lane & 15);
                b[nf] = *(const bf16x8*)((char*)Bb[cur] + n*64 + ((cd ^ ((n >> 1) & 3)) << 4));
            }
            #pragma unroll
            for (int mf = 0; mf < 2; mf++)
                #pragma unroll
                for (int nf = 0; nf < 8; nf++)
                    acc[mf][nf] = __builtin_amdgcn_mfma_f32_16x16x32_bf16(a[mf], b[nf], acc[mf][nf], 0, 0, 0);
        }

        if (c == 15){
            __syncthreads();   // all waves done reading X from AH
            #pragma unroll
            for (int mf = 0; mf < 2; mf++){
                #pragma unroll
                for (int nf = 0; nf < 8; nf++){
                    int col = wn*128 + nf*16 + (lane & 15);
                    #pragma unroll
                    for (int i = 0; i < 4; i++){
                        int r = wm*32 + mf*16 + ((lane >> 4) << 2) + i;
                        float h = acc[mf][nf][i] + bias1[nf];
                        h = h > 0.f ? h : 0.f;
                        char* p = (char*)AH + r*1024 + ((((col >> 3) ^ (r & 7)) << 4)) + (col & 7)*2;
                        *(unsigned short*)p = f2bf(h);
                        acc[mf][nf][i] = 0.f;
                    }
                }
            }
        }

        if (c < 31){
            char* lb = (char*)Bb[cur ^ 1];
            #pragma unroll
            for (int j = 0; j < 4; j++){
                int m = j*512 + tid; int n = m >> 2, cd = m & 3;
                *(bf16x8*)(lb + n*64 + ((cd ^ ((n >> 1) & 3)) << 4)) = stg[j];
            }
        }
        __syncthreads();
        cur ^= 1;
    }

    // epilogue: o = acc + b2; y[tok] += w * o
    #pragma unroll
    for (int mf = 0; mf < 2; mf++){
        #pragma unroll
        for (int i = 0; i < 4; i++){
            int rl = wm*32 + mf*16 + ((lane >> 4) << 2) + i;
            int gr = r0 + rl;
            if (gr < cnt){
                int   tk = toks[e*CAP + gr];
                float w  = wts[e*CAP + gr];
                float* yr = y + (size_t)tk * DD;
                #pragma unroll
                for (int nf = 0; nf < 8; nf++){
                    int col = wn*128 + nf*16 + (lane & 15);
                    atomicAdd(yr + col, w * (acc[mf][nf][i] + bias2[nf]));
                }
            }
        }
    }
}

extern "C" void kernel_launch(void* const* d_in, const int* in_sizes, int n_in,
                              void* d_out, int out_size, void* d_ws, size_t ws_size,
                              hipStream_t stream)
{
    const float* x  = (const float*)d_in[0];
    const float* Wg = (const float*)d_in[1];
    const float* W1 = (const float*)d_in[2];
    const float* b1 = (const float*)d_in[3];
    const float* W2 = (const float*)d_in[4];
    const float* b2 = (const float*)d_in[5];
    float* y = (float*)d_out;

    char* ws = (char*)d_ws;
    unsigned short* W1T = (unsigned short*)(ws);
    unsigned short* W2T = (unsigned short*)(ws + 16777216);
    int*   counts = (int*)  (ws + 33554432);
    int*   toks   = (int*)  (ws + 33554432 + 256);
    float* wts    = (float*)(ws + 33554432 + 256 + 655360);

    hipMemsetAsync(counts, 0, 256, stream);
    hipLaunchKernelGGL(k_wconv, dim3(4096), dim3(256), 0, stream, W1, W2, W1T, W2T);
    hipLaunchKernelGGL(k_gate,  dim3(BT/GTOK), dim3(256), 0, stream, x, Wg, y, counts, toks, wts);
    hipLaunchKernelGGL(k_ffn,   dim3(NE*NRB), dim3(512), 0, stream, x, W1T, W2T, b1, b2, counts, toks, wts, y);
}

// Round 4
// 683.874 us; speedup vs baseline: 2.8313x; 2.5602x over previous
//
#include <hip/hip_runtime.h>
#include <hip/hip_bf16.h>

#define BT 65536
#define DD 512
#define HH 512
#define NE 32
#define CAP 5120
#define BM 64
#define NRB 80   /* CAP/BM */
#define GTOK 256 /* tokens per gate block */

typedef float  f32x4  __attribute__((ext_vector_type(4)));
typedef short  bf16x8 __attribute__((ext_vector_type(8)));

__device__ __forceinline__ unsigned short f2bf(float f){
    unsigned int u = __builtin_bit_cast(unsigned int, f);
    unsigned int r = (u + 0x7fffu + ((u >> 16) & 1u)) >> 16;
    return (unsigned short)r;
}

// ---------------- weight transpose + bf16 convert ----------------
// W[e][k][n] fp32  ->  WT[e][n][k] bf16
__global__ __launch_bounds__(256) void k_wconv(
    const float* __restrict__ W1, const float* __restrict__ W2,
    unsigned short* __restrict__ W1T, unsigned short* __restrict__ W2T)
{
    int bid = blockIdx.x;
    const float* src = W1; unsigned short* dst = W1T;
    if (bid >= 2048){ src = W2; dst = W2T; bid -= 2048; }
    int e    = bid >> 6;
    int trow = (bid >> 3) & 7;   // k-tile
    int tcol = bid & 7;          // n-tile
    __shared__ float tile[64][65];
    const float* base = src + ((size_t)e << 18);
    int t = threadIdx.x;
    #pragma unroll
    for (int i = 0; i < 16; i++){
        int idx = i*256 + t;
        int k = idx >> 6, n = idx & 63;
        tile[k][n] = base[(size_t)(trow*64 + k)*512 + tcol*64 + n];
    }
    __syncthreads();
    unsigned short* ob = dst + ((size_t)e << 18);
    #pragma unroll
    for (int i = 0; i < 16; i++){
        int idx = i*256 + t;
        int n = idx >> 6, k = idx & 63;
        ob[(size_t)(tcol*64 + n)*512 + trow*64 + k] = f2bf(tile[k][n]);
    }
}

// ---------------- gating v4: slim per-thread fp32 GEMM, Wg via uniform (scalar) loads ----------------
__global__ __launch_bounds__(256) void k_gate(
    const float* __restrict__ x, const float* __restrict__ Wg,
    float* __restrict__ y, int* __restrict__ counts,
    int* __restrict__ toks, float* __restrict__ wts)
{
    __shared__ int lcnt[NE], lbase[NE];

    int tid = threadIdx.x;
    int r0  = blockIdx.x * GTOK;
    int tok = r0 + tid;

    const float* xr = x + (size_t)tok * DD;

    float acc[NE];
    #pragma unroll
    for (int n = 0; n < NE; n++) acc[n] = 0.f;

    // Main GEMM: per-thread row dot all 32 experts.
    // Wg addresses are wave-uniform (loop-counter only) -> scalar loads.
    #pragma unroll 1
    for (int d = 0; d < DD; d += 8){
        float4 xa = *(const float4*)(xr + d);
        float4 xb = *(const float4*)(xr + d + 4);
        #pragma unroll
        for (int j = 0; j < 8; j++){
            float xv = (j < 4) ? ((j==0)?xa.x:(j==1)?xa.y:(j==2)?xa.z:xa.w)
                               : ((j==4)?xb.x:(j==5)?xb.y:(j==6)?xb.z:xb.w);
            const float4* wr = (const float4*)(Wg + (size_t)(d + j)*NE);
            #pragma unroll
            for (int q = 0; q < 8; q++){
                float4 w4 = wr[q];
                acc[q*4+0] = fmaf(xv, w4.x, acc[q*4+0]);
                acc[q*4+1] = fmaf(xv, w4.y, acc[q*4+1]);
                acc[q*4+2] = fmaf(xv, w4.z, acc[q*4+2]);
                acc[q*4+3] = fmaf(xv, w4.w, acc[q*4+3]);
            }
        }
    }

    // top-3 in fp32 (strict > keeps lowest index on ties, matching lax.top_k)
    float v1 = -1e30f; int i1 = -1;
    #pragma unroll
    for (int n = 0; n < NE; n++) if (acc[n] > v1){ v1 = acc[n]; i1 = n; }
    float v2 = -1e30f; int i2 = -1;
    #pragma unroll
    for (int n = 0; n < NE; n++) if (n != i1 && acc[n] > v2){ v2 = acc[n]; i2 = n; }
    float v3 = -1e30f;
    #pragma unroll
    for (int n = 0; n < NE; n++) if (n != i1 && n != i2 && acc[n] > v3) v3 = acc[n];

    float w1, w2;
    if (v2 - v3 >= 1e-4f){
        // common path: fp32 gap is decisive (fp32 accumulation error ~1e-6)
        double ex  = exp((double)v2 - (double)v1);
        double inv = 1.0 / (1.0 + ex);
        w1 = (float)inv; w2 = (float)(ex * inv);
    } else {
        // rare (~1e-3): resolve the {top2} set among near-tie candidates in fp64.
        float thresh = v2 - 1e-3f;
        unsigned cmask = 0u;
        #pragma unroll
        for (int n = 0; n < NE; n++) cmask |= (acc[n] >= thresh) ? (1u << n) : 0u;

        double dv1 = -1.0e300, dv2 = -1.0e300; int di1 = -1, di2 = -1;
        #pragma unroll 1
        for (int n = 0; n < NE; n++){
            if (!((cmask >> n) & 1u)) continue;
            double s0 = 0.0, s1 = 0.0, s2 = 0.0, s3 = 0.0;
            #pragma unroll 4
            for (int d = 0; d < DD; d += 4){
                s0 = fma((double)xr[d+0], (double)Wg[(size_t)(d+0)*NE + n], s0);
                s1 = fma((double)xr[d+1], (double)Wg[(size_t)(d+1)*NE + n], s1);
                s2 = fma((double)xr[d+2], (double)Wg[(size_t)(d+2)*NE + n], s2);
                s3 = fma((double)xr[d+3], (double)Wg[(size_t)(d+3)*NE + n], s3);
            }
            double s = (s0 + s1) + (s2 + s3);
            if (s > dv1){ dv2 = dv1; di2 = di1; dv1 = s; di1 = n; }
            else if (s > dv2){ dv2 = s; di2 = n; }
        }
        i1 = di1; i2 = di2;
        double ex  = exp(dv2 - dv1);
        double inv = 1.0 / (1.0 + ex);
        w1 = (float)inv; w2 = (float)(ex * inv);
    }

    // two-level slot assignment
    if (tid < NE) lcnt[tid] = 0;
    __syncthreads();
    int s1 = atomicAdd(&lcnt[i1], 1);
    int s2 = atomicAdd(&lcnt[i2], 1);
    __syncthreads();
    if (tid < NE && lcnt[tid] > 0) lbase[tid] = atomicAdd(&counts[tid], lcnt[tid]);
    __syncthreads();
    int g1 = lbase[i1] + s1;
    int g2 = lbase[i2] + s2;
    bool k1 = g1 < CAP, k2 = g2 < CAP;
    if (k1){ toks[i1*CAP + g1] = tok; wts[i1*CAP + g1] = w1; }
    if (k2){ toks[i2*CAP + g2] = tok; wts[i2*CAP + g2] = w2; }

    // cooperative coalesced y zero for this block's 256 rows
    float4 z4; z4.x = 0.f; z4.y = 0.f; z4.z = 0.f; z4.w = 0.f;
    float4* yb = (float4*)(y + (size_t)r0 * DD);
    #pragma unroll 1
    for (int i = 0; i < 128; i++) yb[i*256 + tid] = z4;
    __syncthreads();
    if (!(k1 | k2)){   // passthrough (statistically never happens)
        const float4* xr4 = (const float4*)(x + (size_t)tok * DD);
        float4* yr4 = (float4*)(y + (size_t)tok * DD);
        #pragma unroll 1
        for (int j = 0; j < 128; j++) yr4[j] = xr4[j];
    }
}

// ---------------- fused expert FFN: relu(Xg@W1+b1)@W2+b2, scatter-add ----------------
__global__ __launch_bounds__(512, 2) void k_ffn(
    const float* __restrict__ x,
    const unsigned short* __restrict__ W1T,
    const unsigned short* __restrict__ W2T,
    const float* __restrict__ b1, const float* __restrict__ b2,
    const int* __restrict__ counts,
    const int* __restrict__ toks, const float* __restrict__ wts,
    float* __restrict__ y)
{
    __shared__ unsigned char AH[64 * 1024];      // 64 rows x 512 bf16, 16B-chunk XOR swizzle (r&7)
    __shared__ unsigned char Bb[2][32 * 1024];   // 512 rows x 32 bf16 (64B rows), chunk XOR ((n>>1)&3)

    int e  = blockIdx.x / NRB;
    int rb = blockIdx.x % NRB;
    int cnt = counts[e]; if (cnt > CAP) cnt = CAP;
    int r0 = rb * BM;
    if (r0 >= cnt) return;

    int tid  = threadIdx.x;
    int lane = tid & 63;
    int wid  = tid >> 6;
    int wm = wid >> 2;       // 0..1 : 32-row half
    int wn = wid & 3;        // 0..3 : 128-col slice

    // ---- stage A: gather x rows, convert to bf16, swizzled ----
    {
        int row = tid >> 3, seg = tid & 7;
        int gr  = r0 + row;
        char* rowb = (char*)AH + row * 1024;
        int rsw = (row & 7) << 4;
        if (gr < cnt){
            int tk = toks[e*CAP + gr];
            const float4* src = (const float4*)(x + (size_t)tk*DD + seg*64);
            #pragma unroll
            for (int j = 0; j < 8; j++){
                float4 f0 = src[2*j], f1 = src[2*j+1];
                bf16x8 p;
                p[0]=(short)f2bf(f0.x); p[1]=(short)f2bf(f0.y); p[2]=(short)f2bf(f0.z); p[3]=(short)f2bf(f0.w);
                p[4]=(short)f2bf(f1.x); p[5]=(short)f2bf(f1.y); p[6]=(short)f2bf(f1.z); p[7]=(short)f2bf(f1.w);
                int chunk = seg*8 + j;
                *(bf16x8*)(rowb + ((chunk << 4) ^ rsw)) = p;
            }
        } else {
            bf16x8 zz = (bf16x8)0;
            #pragma unroll
            for (int j = 0; j < 8; j++){
                int chunk = seg*8 + j;
                *(bf16x8*)(rowb + ((chunk << 4) ^ rsw)) = zz;
            }
        }
    }

    float bias1[8], bias2[8];
    #pragma unroll
    for (int nf = 0; nf < 8; nf++){
        int col = wn*128 + nf*16 + (lane & 15);
        bias1[nf] = b1[e*HH + col];
        bias2[nf] = b2[e*DD + col];
    }

    f32x4 acc[2][8];
    #pragma unroll
    for (int mf = 0; mf < 2; mf++)
        #pragma unroll
        for (int nf = 0; nf < 8; nf++)
            acc[mf][nf] = (f32x4)0.f;

    // B chunk c: layer = c>>4, kk = (c&15)*32; thread stages 4 x 16B
    bf16x8 stg[4];
    {   // prologue chunk 0
        const unsigned short* Wb = W1T + ((size_t)e << 18);
        #pragma unroll
        for (int j = 0; j < 4; j++){
            int m = j*512 + tid; int n = m >> 2, cd = m & 3;
            stg[j] = *(const bf16x8*)(Wb + (size_t)n*512 + cd*8);
        }
        char* lb = (char*)Bb[0];
        #pragma unroll
        for (int j = 0; j < 4; j++){
            int m = j*512 + tid; int n = m >> 2, cd = m & 3;
            *(bf16x8*)(lb + n*64 + ((cd ^ ((n >> 1) & 3)) << 4)) = stg[j];
        }
    }
    __syncthreads();

    int cur = 0;
    #pragma unroll 1
    for (int c = 0; c < 32; c++){
        if (c < 31){
            int cn = c + 1;
            const unsigned short* Wb = ((cn < 16) ? W1T : W2T) + ((size_t)e << 18) + (cn & 15)*32;
            #pragma unroll
            for (int j = 0; j < 4; j++){
                int m = j*512 + tid; int n = m >> 2, cd = m & 3;
                stg[j] = *(const bf16x8*)(Wb + (size_t)n*512 + cd*8);
            }
        }
        // compute chunk c
        {
            bf16x8 a[2], b[8];
            int kchunk0 = ((c & 15) << 2) + (lane >> 4);
            #pragma unroll
            for (int mf = 0; mf < 2; mf++){
                int r = wm*32 + mf*16 + (lane & 15);
                a[mf] = *(const bf16x8*)((char*)AH + r*1024 + ((kchunk0 ^ (r & 7)) << 4));
            }
            int cd = lane >> 4;
            #pragma unroll
            for (int nf = 0; nf < 8; nf++){
                int n = wn*128 + nf*16 + (lane & 15);
                b[nf] = *(const bf16x8*)((char*)Bb[cur] + n*64 + ((cd ^ ((n >> 1) & 3)) << 4));
            }
            #pragma unroll
            for (int mf = 0; mf < 2; mf++)
                #pragma unroll
                for (int nf = 0; nf < 8; nf++)
                    acc[mf][nf] = __builtin_amdgcn_mfma_f32_16x16x32_bf16(a[mf], b[nf], acc[mf][nf], 0, 0, 0);
        }

        if (c == 15){
            __syncthreads();   // all waves done reading X from AH
            #pragma unroll
            for (int mf = 0; mf < 2; mf++){
                #pragma unroll
                for (int nf = 0; nf < 8; nf++){
                    int col = wn*128 + nf*16 + (lane & 15);
                    #pragma unroll
                    for (int i = 0; i < 4; i++){
                        int r = wm*32 + mf*16 + ((lane >> 4) << 2) + i;
                        float h = acc[mf][nf][i] + bias1[nf];
                        h = h > 0.f ? h : 0.f;
                        char* p = (char*)AH + r*1024 + ((((col >> 3) ^ (r & 7)) << 4)) + (col & 7)*2;
                        *(unsigned short*)p = f2bf(h);
                        acc[mf][nf][i] = 0.f;
                    }
                }
            }
        }

        if (c < 31){
            char* lb = (char*)Bb[cur ^ 1];
            #pragma unroll
            for (int j = 0; j < 4; j++){
                int m = j*512 + tid; int n = m >> 2, cd = m & 3;
                *(bf16x8*)(lb + n*64 + ((cd ^ ((n >> 1) & 3)) << 4)) = stg[j];
            }
        }
        __syncthreads();
        cur ^= 1;
    }

    // epilogue: o = acc + b2; y[tok] += w * o
    #pragma unroll
    for (int mf = 0; mf < 2; mf++){
        #pragma unroll
        for (int i = 0; i < 4; i++){
            int rl = wm*32 + mf*16 + ((lane >> 4) << 2) + i;
            int gr = r0 + rl;
            if (gr < cnt){
                int   tk = toks[e*CAP + gr];
                float w  = wts[e*CAP + gr];
                float* yr = y + (size_t)tk * DD;
                #pragma unroll
                for (int nf = 0; nf < 8; nf++){
                    int col = wn*128 + nf*16 + (lane & 15);
                    atomicAdd(yr + col, w * (acc[mf][nf][i] + bias2[nf]));
                }
            }
        }
    }
}

extern "C" void kernel_launch(void* const* d_in, const int* in_sizes, int n_in,
                              void* d_out, int out_size, void* d_ws, size_t ws_size,
                              hipStream_t stream)
{
    const float* x  = (const float*)d_in[0];
    const float* Wg = (const float*)d_in[1];
    const float* W1 = (const float*)d_in[2];
    const float* b1 = (const float*)d_in[3];
    const float* W2 = (const float*)d_in[4];
    const float* b2 = (const float*)d_in[5];
    float* y = (float*)d_out;

    char* ws = (char*)d_ws;
    unsigned short* W1T = (unsigned short*)(ws);
    unsigned short* W2T = (unsigned short*)(ws + 16777216);
    int*   counts = (int*)  (ws + 33554432);
    int*   toks   = (int*)  (ws + 33554432 + 256);
    float* wts    = (float*)(ws + 33554432 + 256 + 655360);

    hipMemsetAsync(counts, 0, 256, stream);
    hipLaunchKernelGGL(k_wconv, dim3(4096), dim3(256), 0, stream, W1, W2, W1T, W2T);
    hipLaunchKernelGGL(k_gate,  dim3(BT/GTOK), dim3(256), 0, stream, x, Wg, y, counts, toks, wts);
    hipLaunchKernelGGL(k_ffn,   dim3(NE*NRB), dim3(512), 0, stream, x, W1T, W2T, b1, b2, counts, toks, wts, y);
}

// Round 5
// 516.471 us; speedup vs baseline: 3.7490x; 1.3241x over previous
//
#include <hip/hip_runtime.h>
#include <hip/hip_bf16.h>

#define BT 65536
#define DD 512
#define HH 512
#define NE 32
#define CAP 5120
#define BM 64
#define NRB 80   /* CAP/BM */
#define GTOK 128 /* tokens per gate block */

typedef float  f32x4  __attribute__((ext_vector_type(4)));
typedef short  bf16x8 __attribute__((ext_vector_type(8)));

__device__ __forceinline__ unsigned short f2bf(float f){
    unsigned int u = __builtin_bit_cast(unsigned int, f);
    unsigned int r = (u + 0x7fffu + ((u >> 16) & 1u)) >> 16;
    return (unsigned short)r;
}

// ---------------- weight convert to MFMA-fragment-tiled bf16 ----------------
// W[e][k][n] fp32 -> Wf[e][nt(32)][kc(16)][lane(64)][8] bf16, where for fragment
// (nt,kc): lane holds B[k = kc*32 + (lane>>4)*8 + j][n = nt*16 + (lane&15)].
// A wave's b-fragment load is then one coalesced 1KB global_load_dwordx4.
__global__ __launch_bounds__(256) void k_wconv(
    const float* __restrict__ W1, const float* __restrict__ W2,
    unsigned short* __restrict__ W1f, unsigned short* __restrict__ W2f)
{
    int b = blockIdx.x;                    // 512 blocks
    int w = b >> 8;                        // 0: W1, 1: W2
    int e = (b >> 3) & 31;
    int kq = b & 7;                        // k-range [kq*64, kq*64+64)
    const float* src = (w ? W2 : W1) + ((size_t)e << 18);
    unsigned short* dst = (w ? W2f : W1f) + ((size_t)e << 18);
    int t = threadIdx.x;
    #pragma unroll 1
    for (int kg = 0; kg < 8; kg++){
        int k0 = kq*64 + kg*8;
        #pragma unroll
        for (int ng = 0; ng < 2; ng++){
            int n = ng*256 + t;
            unsigned short v[8];
            #pragma unroll
            for (int j = 0; j < 8; j++)
                v[j] = f2bf(src[(size_t)(k0 + j)*512 + n]);
            int nt = n >> 4, kc = k0 >> 5, ln = ((k0 >> 3) & 3)*16 + (n & 15);
            *(bf16x8*)(dst + (((size_t)(nt*16 + kc)*64 + ln) << 3)) = *(bf16x8*)v;
        }
    }
}

// ---------------- gating: slim per-thread fp32 GEMM, Wg via uniform (scalar) loads ----------------
__global__ __launch_bounds__(256) void k_gate(
    const float* __restrict__ x, const float* __restrict__ Wg,
    float* __restrict__ y, int* __restrict__ counts,
    int* __restrict__ toks, float* __restrict__ wts)
{
    __shared__ int lcnt[NE], lbase[NE];

    int tid = threadIdx.x;
    int r0  = blockIdx.x * GTOK;
    int tok = r0 + (tid & (GTOK - 1));
    // NOTE: with GTOK=128 and 256 threads, two threads share a token? No:
    // keep 1 thread = 1 token; block has 256 threads but GTOK=128 would waste half.
    // Instead: 256 threads, 256 tokens per block — keep GTOK==256 semantics via grid.
    tok = r0 * 2 + tid;                 // grid uses BT/256 blocks *2?  (see launch: grid = BT/256, GTOK unused)
    tok = blockIdx.x * 256 + tid;       // final: 1 token per thread, 256 per block

    const float* xr = x + (size_t)tok * DD;

    float acc[NE];
    #pragma unroll
    for (int n = 0; n < NE; n++) acc[n] = 0.f;

    #pragma unroll 1
    for (int d = 0; d < DD; d += 8){
        float4 xa = *(const float4*)(xr + d);
        float4 xb = *(const float4*)(xr + d + 4);
        #pragma unroll
        for (int j = 0; j < 8; j++){
            float xv = (j < 4) ? ((j==0)?xa.x:(j==1)?xa.y:(j==2)?xa.z:xa.w)
                               : ((j==4)?xb.x:(j==5)?xb.y:(j==6)?xb.z:xb.w);
            const float4* wr = (const float4*)(Wg + (size_t)(d + j)*NE);
            #pragma unroll
            for (int q = 0; q < 8; q++){
                float4 w4 = wr[q];
                acc[q*4+0] = fmaf(xv, w4.x, acc[q*4+0]);
                acc[q*4+1] = fmaf(xv, w4.y, acc[q*4+1]);
                acc[q*4+2] = fmaf(xv, w4.z, acc[q*4+2]);
                acc[q*4+3] = fmaf(xv, w4.w, acc[q*4+3]);
            }
        }
    }

    // top-3 in fp32 (strict > keeps lowest index on ties, matching lax.top_k)
    float v1 = -1e30f; int i1 = -1;
    #pragma unroll
    for (int n = 0; n < NE; n++) if (acc[n] > v1){ v1 = acc[n]; i1 = n; }
    float v2 = -1e30f; int i2 = -1;
    #pragma unroll
    for (int n = 0; n < NE; n++) if (n != i1 && acc[n] > v2){ v2 = acc[n]; i2 = n; }
    float v3 = -1e30f;
    #pragma unroll
    for (int n = 0; n < NE; n++) if (n != i1 && n != i2 && acc[n] > v3) v3 = acc[n];

    float w1, w2;
    if (v2 - v3 >= 1e-4f){
        double ex  = exp((double)v2 - (double)v1);
        double inv = 1.0 / (1.0 + ex);
        w1 = (float)inv; w2 = (float)(ex * inv);
    } else {
        // rare (~1e-3): resolve the {top2} set among near-tie candidates in fp64.
        float thresh = v2 - 1e-3f;
        unsigned cmask = 0u;
        #pragma unroll
        for (int n = 0; n < NE; n++) cmask |= (acc[n] >= thresh) ? (1u << n) : 0u;

        double dv1 = -1.0e300, dv2 = -1.0e300; int di1 = -1, di2 = -1;
        #pragma unroll 1
        for (int n = 0; n < NE; n++){
            if (!((cmask >> n) & 1u)) continue;
            double s0 = 0.0, s1 = 0.0, s2 = 0.0, s3 = 0.0;
            #pragma unroll 4
            for (int d = 0; d < DD; d += 4){
                s0 = fma((double)xr[d+0], (double)Wg[(size_t)(d+0)*NE + n], s0);
                s1 = fma((double)xr[d+1], (double)Wg[(size_t)(d+1)*NE + n], s1);
                s2 = fma((double)xr[d+2], (double)Wg[(size_t)(d+2)*NE + n], s2);
                s3 = fma((double)xr[d+3], (double)Wg[(size_t)(d+3)*NE + n], s3);
            }
            double s = (s0 + s1) + (s2 + s3);
            if (s > dv1){ dv2 = dv1; di2 = di1; dv1 = s; di1 = n; }
            else if (s > dv2){ dv2 = s; di2 = n; }
        }
        i1 = di1; i2 = di2;
        double ex  = exp(dv2 - dv1);
        double inv = 1.0 / (1.0 + ex);
        w1 = (float)inv; w2 = (float)(ex * inv);
    }

    // two-level slot assignment
    if (tid < NE) lcnt[tid] = 0;
    __syncthreads();
    int s1 = atomicAdd(&lcnt[i1], 1);
    int s2 = atomicAdd(&lcnt[i2], 1);
    __syncthreads();
    if (tid < NE && lcnt[tid] > 0) lbase[tid] = atomicAdd(&counts[tid], lcnt[tid]);
    __syncthreads();
    int g1 = lbase[i1] + s1;
    int g2 = lbase[i2] + s2;
    bool k1 = g1 < CAP, k2 = g2 < CAP;
    if (k1){ toks[i1*CAP + g1] = tok; wts[i1*CAP + g1] = w1; }
    if (k2){ toks[i2*CAP + g2] = tok; wts[i2*CAP + g2] = w2; }

    // cooperative coalesced y zero for this block's 256 rows
    float4 z4; z4.x = 0.f; z4.y = 0.f; z4.z = 0.f; z4.w = 0.f;
    float4* yb = (float4*)(y + (size_t)blockIdx.x * 256 * DD);
    #pragma unroll 1
    for (int i = 0; i < 128; i++) yb[i*256 + tid] = z4;
    __syncthreads();
    if (!(k1 | k2)){   // passthrough (statistically never happens)
        const float4* xr4 = (const float4*)(x + (size_t)tok * DD);
        float4* yr4 = (float4*)(y + (size_t)tok * DD);
        #pragma unroll 1
        for (int j = 0; j < 128; j++) yr4[j] = xr4[j];
    }
}

// ---------------- fused expert FFN v2: B streamed from L2, A/h in LDS, 3 barriers ----------------
__global__ __launch_bounds__(512, 4) void k_ffn(
    const float* __restrict__ x,
    const unsigned short* __restrict__ W1f,
    const unsigned short* __restrict__ W2f,
    const float* __restrict__ b1, const float* __restrict__ b2,
    const int* __restrict__ counts,
    const int* __restrict__ toks, const float* __restrict__ wts,
    float* __restrict__ y)
{
    __shared__ unsigned char AH[64 * 1024];   // 64 rows x 512 bf16, 16B-chunk XOR swizzle (r&7)

    int e  = blockIdx.x / NRB;
    int rb = blockIdx.x % NRB;
    int cnt = counts[e]; if (cnt > CAP) cnt = CAP;
    int r0 = rb * BM;
    if (r0 >= cnt) return;

    int tid  = threadIdx.x;
    int lane = tid & 63;
    int wn   = tid >> 6;      // 8 waves, each owns a 64x64 output tile (cols wn*64..wn*64+63)

    // ---- stage A: gather x rows, convert to bf16, swizzled ----
    {
        int row = tid >> 3, seg = tid & 7;
        int gr  = r0 + row;
        char* rowb = (char*)AH + row * 1024;
        int rsw = (row & 7) << 4;
        if (gr < cnt){
            int tk = toks[e*CAP + gr];
            const float4* src = (const float4*)(x + (size_t)tk*DD + seg*64);
            #pragma unroll
            for (int j = 0; j < 8; j++){
                float4 f0 = src[2*j], f1 = src[2*j+1];
                bf16x8 p;
                p[0]=(short)f2bf(f0.x); p[1]=(short)f2bf(f0.y); p[2]=(short)f2bf(f0.z); p[3]=(short)f2bf(f0.w);
                p[4]=(short)f2bf(f1.x); p[5]=(short)f2bf(f1.y); p[6]=(short)f2bf(f1.z); p[7]=(short)f2bf(f1.w);
                int chunk = seg*8 + j;
                *(bf16x8*)(rowb + ((chunk << 4) ^ rsw)) = p;
            }
        } else {
            bf16x8 zz = (bf16x8)0;
            #pragma unroll
            for (int j = 0; j < 8; j++){
                int chunk = seg*8 + j;
                *(bf16x8*)(rowb + ((chunk << 4) ^ rsw)) = zz;
            }
        }
    }
    __syncthreads();

    f32x4 acc[4][4];
    #pragma unroll
    for (int mf = 0; mf < 4; mf++)
        #pragma unroll
        for (int nf = 0; nf < 4; nf++)
            acc[mf][nf] = (f32x4)0.f;

    // ---- layer 1: acc += X @ W1 (b-fragments streamed from L2) ----
    {
        const unsigned short* Wb = W1f + ((size_t)e << 18);
        #pragma unroll 1
        for (int c = 0; c < 16; c++){
            bf16x8 b[4], a[4];
            #pragma unroll
            for (int nf = 0; nf < 4; nf++)
                b[nf] = *(const bf16x8*)(Wb + (((size_t)((wn*4 + nf)*16 + c)*64 + lane) << 3));
            #pragma unroll
            for (int mf = 0; mf < 4; mf++){
                int r = mf*16 + (lane & 15);
                int chunk = (c*4 + (lane >> 4)) ^ (r & 7);
                a[mf] = *(const bf16x8*)((char*)AH + r*1024 + (chunk << 4));
            }
            #pragma unroll
            for (int mf = 0; mf < 4; mf++)
                #pragma unroll
                for (int nf = 0; nf < 4; nf++)
                    acc[mf][nf] = __builtin_amdgcn_mfma_f32_16x16x32_bf16(a[mf], b[nf], acc[mf][nf], 0, 0, 0);
        }
    }
    __syncthreads();   // all waves done reading X

    // ---- h = relu(acc + b1) -> AH (bf16, swizzled) ----
    #pragma unroll
    for (int nf = 0; nf < 4; nf++){
        int col = wn*64 + nf*16 + (lane & 15);
        float bb = b1[e*HH + col];
        #pragma unroll
        for (int mf = 0; mf < 4; mf++){
            #pragma unroll
            for (int i = 0; i < 4; i++){
                int r = mf*16 + ((lane >> 4) << 2) + i;
                float h = acc[mf][nf][i] + bb;
                h = h > 0.f ? h : 0.f;
                char* p = (char*)AH + r*1024 + ((((col >> 3) ^ (r & 7)) << 4)) + (col & 7)*2;
                *(unsigned short*)p = f2bf(h);
                acc[mf][nf][i] = 0.f;
            }
        }
    }
    __syncthreads();

    // ---- layer 2: acc += h @ W2 ----
    {
        const unsigned short* Wb = W2f + ((size_t)e << 18);
        #pragma unroll 1
        for (int c = 0; c < 16; c++){
            bf16x8 b[4], a[4];
            #pragma unroll
            for (int nf = 0; nf < 4; nf++)
                b[nf] = *(const bf16x8*)(Wb + (((size_t)((wn*4 + nf)*16 + c)*64 + lane) << 3));
            #pragma unroll
            for (int mf = 0; mf < 4; mf++){
                int r = mf*16 + (lane & 15);
                int chunk = (c*4 + (lane >> 4)) ^ (r & 7);
                a[mf] = *(const bf16x8*)((char*)AH + r*1024 + (chunk << 4));
            }
            #pragma unroll
            for (int mf = 0; mf < 4; mf++)
                #pragma unroll
                for (int nf = 0; nf < 4; nf++)
                    acc[mf][nf] = __builtin_amdgcn_mfma_f32_16x16x32_bf16(a[mf], b[nf], acc[mf][nf], 0, 0, 0);
        }
    }

    // ---- epilogue: y[tok] += w * (acc + b2) ----
    float bias2[4];
    #pragma unroll
    for (int nf = 0; nf < 4; nf++)
        bias2[nf] = b2[e*DD + wn*64 + nf*16 + (lane & 15)];

    #pragma unroll
    for (int mf = 0; mf < 4; mf++){
        #pragma unroll
        for (int i = 0; i < 4; i++){
            int rl = mf*16 + ((lane >> 4) << 2) + i;
            int gr = r0 + rl;
            if (gr < cnt){
                int   tk = toks[e*CAP + gr];
                float w  = wts[e*CAP + gr];
                float* yr = y + (size_t)tk * DD;
                #pragma unroll
                for (int nf = 0; nf < 4; nf++){
                    int col = wn*64 + nf*16 + (lane & 15);
                    atomicAdd(yr + col, w * (acc[mf][nf][i] + bias2[nf]));
                }
            }
        }
    }
}

extern "C" void kernel_launch(void* const* d_in, const int* in_sizes, int n_in,
                              void* d_out, int out_size, void* d_ws, size_t ws_size,
                              hipStream_t stream)
{
    const float* x  = (const float*)d_in[0];
    const float* Wg = (const float*)d_in[1];
    const float* W1 = (const float*)d_in[2];
    const float* b1 = (const float*)d_in[3];
    const float* W2 = (const float*)d_in[4];
    const float* b2 = (const float*)d_in[5];
    float* y = (float*)d_out;

    char* ws = (char*)d_ws;
    unsigned short* W1f = (unsigned short*)(ws);
    unsigned short* W2f = (unsigned short*)(ws + 16777216);
    int*   counts = (int*)  (ws + 33554432);
    int*   toks   = (int*)  (ws + 33554432 + 256);
    float* wts    = (float*)(ws + 33554432 + 256 + 655360);

    hipMemsetAsync(counts, 0, 256, stream);
    hipLaunchKernelGGL(k_wconv, dim3(512), dim3(256), 0, stream, W1, W2, W1f, W2f);
    hipLaunchKernelGGL(k_gate,  dim3(BT/256), dim3(256), 0, stream, x, Wg, y, counts, toks, wts);
    hipLaunchKernelGGL(k_ffn,   dim3(NE*NRB), dim3(512), 0, stream, x, W1f, W2f, b1, b2, counts, toks, wts, y);
}